// Round 5
// baseline (225.197 us; speedup 1.0000x reference)
//
#include <hip/hip_runtime.h>
#include <stdint.h>
#include <stddef.h>

#define GLOBAL_AS __attribute__((address_space(1)))
#define LDS_AS    __attribute__((address_space(3)))

typedef __bf16 bf16x8 __attribute__((ext_vector_type(8)));
typedef float  f32x4  __attribute__((ext_vector_type(4)));

// x(8,256,64,64) fp32, W(128,256,4,4), bias(128,4,4), stride 2 -> out(8,128,130,130) fp32
constexpr int NB = 8, CI = 256, H_ = 64, W_ = 64, CO = 128;
constexpr int OH = 130, OW = 130;
constexpr int PU = 65;               // per-parity output extent u,v in [0,65)
constexpr int PAD = 66;              // padded x extent (zero border ring)
constexpr int NPIX = PU * PU;        // 4225 pixels per batch per parity
constexpr int NTOT = NB * NPIX;      // 33800 flat N
constexpr int NT_N = 133;            // ceil(33800/256)

constexpr size_t XPAD_BYTES = (size_t)NB * PAD * PAD * CI * 2;   // 17,842,176
constexpr size_t A_OFF      = XPAD_BYTES;                         // A_all[512][1024] bf16 (1 MiB)

__device__ __forceinline__ void gload_lds16(const void* g, void* l) {
  __builtin_amdgcn_global_load_lds((GLOBAL_AS void*)g, (LDS_AS void*)l, 16, 0, 0);
}

// ---- P1: x (b,i,h,w) fp32 -> xpadT[b][p][q][i] bf16, zero border ring written here ----
__global__ void prep_x(const float* __restrict__ x, __bf16* __restrict__ xp) {
  __shared__ float tile[64][65];
  const int h   = blockIdx.x;          // 0..65 ; 64 -> zero row 0, 65 -> zero row 65
  const int bat = blockIdx.y;
  const int t   = threadIdx.x;         // 256
  if (h >= 64) {
    const int row = (h == 64) ? 0 : 65;
    __bf16* dst = xp + (size_t)(bat * PAD + row) * PAD * CI;
    bf16x8 z = {};
    for (int idx = t; idx < PAD * CI / 8; idx += 256)
      *(bf16x8*)(dst + (size_t)idx * 8) = z;
    return;
  }
  if (t < 64) {   // zero cols 0 and 65 of padded row h+1
    __bf16* rowp = xp + (size_t)(bat * PAD + h + 1) * PAD * CI;
    bf16x8 z = {};
    int half = t >> 5, part = t & 31;
    *(bf16x8*)(rowp + (size_t)half * 65 * CI + part * 8) = z;
  }
  for (int ch = 0; ch < 4; ++ch) {
    const int i0 = ch * 64;
    const float* src = x + (((size_t)(bat * CI + i0)) * H_ + h) * W_;
    if (ch) __syncthreads();
#pragma unroll
    for (int r = 0; r < 4; ++r) {
      int ii = r * 16 + (t >> 4);
      int ww = (t & 15) * 4;
      float4 v = *(const float4*)(src + (size_t)ii * H_ * W_ + ww);
      tile[ii][ww] = v.x; tile[ii][ww + 1] = v.y; tile[ii][ww + 2] = v.z; tile[ii][ww + 3] = v.w;
    }
    __syncthreads();
    __bf16* dst = xp + ((size_t)(bat * PAD + h + 1) * PAD + 1) * CI + i0;
#pragma unroll
    for (int r = 0; r < 2; ++r) {
      int s  = r * 256 + t;
      int ww = s >> 3;
      int ig = (s & 7) * 8;
      bf16x8 o;
#pragma unroll
      for (int k = 0; k < 8; ++k) o[k] = (__bf16)tile[ig + k][ww];
      *(bf16x8*)(dst + (size_t)ww * CI + ig) = o;
    }
  }
}

// ---- P2: W (o,i,ky,kx) fp32 -> A_all[(py*256 + o*2+px)*1024 + (a*2+c)*256 + i] bf16 ----
// block = one o (128 blocks); thread t = i. Reads 16KB contiguous/block; writes 128B runs.
__global__ void prep_w3(const float* __restrict__ w, __bf16* __restrict__ amat) {
  const int o = blockIdx.x, t = threadIdx.x;
  const float* src = w + (size_t)o * 4096 + t * 16;
  float4 v0 = *(const float4*)(src);
  float4 v1 = *(const float4*)(src + 4);
  float4 v2 = *(const float4*)(src + 8);
  float4 v3 = *(const float4*)(src + 12);
  float vals[16] = {v0.x, v0.y, v0.z, v0.w, v1.x, v1.y, v1.z, v1.w,
                    v2.x, v2.y, v2.z, v2.w, v3.x, v3.y, v3.z, v3.w};
#pragma unroll
  for (int ky = 0; ky < 4; ++ky)
#pragma unroll
    for (int kx = 0; kx < 4; ++kx) {
      const int pyy = ky & 1, a = ky >> 1, pxx = kx & 1, c = kx >> 1;
      amat[((size_t)(pyy * 256 + o * 2 + pxx)) * 1024 + (a * 2 + c) * 256 + t] =
          (__bf16)vals[ky * 4 + kx];
    }
}

// ---- main: BM=256 x BN=256, BK=64, 8 waves, 8-phase counted-vmcnt schedule (m201 port) ----
__global__ __launch_bounds__(512, 2) void deconv_mfma(
    const __bf16* __restrict__ xp, const __bf16* __restrict__ amat,
    const float* __restrict__ bias, float* __restrict__ out) {
  const int wg    = blockIdx.x;        // 266 = 2*133
  const int py    = wg / NT_N;
  const int nt_i  = wg % NT_N;
  const int nBase = nt_i * 256;

  // per buf 64KB: A [0,32768) 256m x 64k ; B [32768,65536) 256n x 64k. Octet-swizzled.
  __shared__ char ldsc[131072] __attribute__((aligned(16)));

  const int t    = threadIdx.x;
  const int wid  = t >> 6, lane = t & 63;
  const int lr   = lane & 15, kg = lane >> 4;
  const int wm   = wid >> 2, wn = wid & 3;     // 2(M) x 4(N) waves; wave tile 128 x 64

  // ---- staging invariants: thread t writes phys chunk p=t&7 of rows r0=t>>3 (+64j, +128h) ----
  const int r0 = t >> 3;
  const int gA = (t & 7) ^ (r0 & 7);           // source k-octet (XOR involution)
  const __bf16* srcA_t = amat + ((size_t)(py * 256 + r0)) * 1024 + gA * 8;
  int obB[2][2];                                // int32 byte-ish offsets (elems) into xp
#pragma unroll
  for (int h = 0; h < 2; ++h)
#pragma unroll
    for (int j = 0; j < 2; ++j) {
      int n = nBase + h * 128 + r0 + 64 * j;
      if (n > NTOT - 1) n = NTOT - 1;          // tail clamp (garbage cols, never stored)
      const int bat = n / NPIX, pr = n % NPIX;
      const int u = pr / PU, v = pr % PU;
      obB[h][j] = ((bat * PAD + u + 1) * PAD + (v + 1)) * CI + gA * 8;
    }

  // ---- fragment read terms (phys octet = logical ^ (row&7)) ----
  const int xorA0 = (kg ^ (lr & 7)) * 16;      // ks=0 ; ks=1 -> ^64
  const int rowA  = (wm * 128 + lr) * 128;     // + mt*2048
  const int rowB  = 32768 + (wn * 64 + lr) * 128;  // + nt*2048

  f32x4 acc[8][4] = {};
  bf16x8 af[8][2], bf[4][2];

#define HSA(buf, tile, h) do {                                                  \
    char* _l = ldsc + (buf) * 65536 + (h) * 16384 + t * 16;                     \
    const __bf16* _s = srcA_t + (size_t)((h) * 128) * 1024 + (tile) * 64;       \
    gload_lds16(_s, _l);                                                        \
    gload_lds16(_s + 64 * 1024, _l + 8192);                                     \
  } while (0)

#define HSB(buf, tile, h) do {                                                  \
    char* _l = ldsc + (buf) * 65536 + 32768 + (h) * 16384 + t * 16;             \
    const int _off = ((tile) & 3) * 64 - (((tile) >> 3) * PAD + (((tile) >> 2) & 1)) * CI; \
    gload_lds16(xp + obB[h][0] + _off, _l);                                     \
    gload_lds16(xp + obB[h][1] + _off, _l + 8192);                              \
  } while (0)

#define RDA(buf, mtb) do {                                                      \
    _Pragma("unroll")                                                           \
    for (int _q = 0; _q < 4; ++_q) {                                            \
      af[(mtb) + _q][0] = *(const bf16x8*)(ldsc + (buf) * 65536 + rowA + ((mtb) + _q) * 2048 + xorA0);        \
      af[(mtb) + _q][1] = *(const bf16x8*)(ldsc + (buf) * 65536 + rowA + ((mtb) + _q) * 2048 + (xorA0 ^ 64)); \
    }                                                                           \
  } while (0)

#define RDB(buf, ntb) do {                                                      \
    _Pragma("unroll")                                                           \
    for (int _q = 0; _q < 2; ++_q) {                                            \
      bf[(ntb) + _q][0] = *(const bf16x8*)(ldsc + (buf) * 65536 + rowB + ((ntb) + _q) * 2048 + xorA0);        \
      bf[(ntb) + _q][1] = *(const bf16x8*)(ldsc + (buf) * 65536 + rowB + ((ntb) + _q) * 2048 + (xorA0 ^ 64)); \
    }                                                                           \
  } while (0)

#define MM(qm, qn) do {                                                         \
    __builtin_amdgcn_s_setprio(1);                                              \
    _Pragma("unroll")                                                           \
    for (int _a = 0; _a < 4; ++_a)                                              \
      _Pragma("unroll")                                                         \
      for (int _b = 0; _b < 2; ++_b) {                                          \
        acc[(qm)*4+_a][(qn)*2+_b] = __builtin_amdgcn_mfma_f32_16x16x32_bf16(    \
            af[(qm)*4+_a][0], bf[(qn)*2+_b][0], acc[(qm)*4+_a][(qn)*2+_b], 0, 0, 0); \
        acc[(qm)*4+_a][(qn)*2+_b] = __builtin_amdgcn_mfma_f32_16x16x32_bf16(    \
            af[(qm)*4+_a][1], bf[(qn)*2+_b][1], acc[(qm)*4+_a][(qn)*2+_b], 0, 0, 0); \
      }                                                                         \
    __builtin_amdgcn_s_setprio(0);                                              \
  } while (0)

#define BAR __builtin_amdgcn_s_barrier()
#define WAITV(n) asm volatile("s_waitcnt vmcnt(" #n ")" ::: "memory")

  // ---- prologue: T0 full, T1 A-halves; wait T0; publish ----
  HSA(0, 0, 0); HSA(0, 0, 1); HSB(0, 0, 0); HSB(0, 0, 1);
  HSA(1, 1, 0); HSA(1, 1, 1);
  WAITV(4);
  BAR;

#pragma unroll 1
  for (int i = 0; i < 8; ++i) {
    const int T1 = 2 * i + 1, P0 = 2 * i + 2, P1 = 2 * i + 3;
    const bool last = (i == 7);
    // K-tile 2i from buf0 (reads front-loaded ph1-2; buf0 refill opens ph3)
    /*ph1*/ RDA(0, 0); RDB(0, 0); HSB(1, T1, 0); BAR; MM(0, 0); BAR;
    /*ph2*/ RDA(0, 4); RDB(0, 2); HSB(1, T1, 1); BAR; MM(1, 1); BAR;
    /*ph3*/ if (!last) HSA(0, P0, 0); BAR; MM(0, 1); BAR;
    /*ph4*/ if (!last) { HSA(0, P0, 1); WAITV(4); } else { WAITV(0); }
            BAR; MM(1, 0); BAR;
    // K-tile 2i+1 from buf1 (refill of buf1 opens ph7)
    /*ph5*/ RDA(1, 0); RDB(1, 0); if (!last) HSB(0, P0, 0); BAR; MM(0, 0); BAR;
    /*ph6*/ RDA(1, 4); RDB(1, 2); if (!last) HSB(0, P0, 1); BAR; MM(1, 1); BAR;
    /*ph7*/ if (!last) HSA(1, P1, 0); BAR; MM(0, 1); BAR;
    /*ph8*/ if (!last) { HSA(1, P1, 1); WAITV(4); }
            BAR; MM(1, 0); BAR;
  }

  // ---- epilogue: D rows r,r+1 are px=0,1 of same o -> dense float2 stores (r2-verified map) ----
#pragma unroll
  for (int mt = 0; mt < 8; ++mt) {
    const int rbase = wm * 128 + mt * 16 + kg * 4;   // D row = (lane>>4)*4 + r [m89-verified]
    const int o0 = rbase >> 1, o1 = o0 + 1;
#pragma unroll
    for (int nt = 0; nt < 4; ++nt) {
      const int n = nBase + wn * 64 + nt * 16 + lr;
      if (n < NTOT) {
        const int bat = n / NPIX, pr = n % NPIX;
        const int u = pr / PU, v = pr % PU;
        const int oy = 2 * u + py;
        const bool a0 = (u <= 63), a1 = (u >= 1);
        const bool c0 = (v <= 63), c1 = (v >= 1);
        auto bs = [&](int o, int px) {
          const float* bp = bias + (size_t)o * 16;
          float s0 = 0.f;
          if (a0 && c0) s0 += bp[py * 4 + px];
          if (a0 && c1) s0 += bp[py * 4 + px + 2];
          if (a1 && c0) s0 += bp[(py + 2) * 4 + px];
          if (a1 && c1) s0 += bp[(py + 2) * 4 + px + 2];
          return s0;
        };
        const size_t b0 = ((size_t)(bat * CO + o0) * OH + oy) * OW + 2 * v;
        const size_t b1 = ((size_t)(bat * CO + o1) * OH + oy) * OW + 2 * v;
        float2 w0, w1;
        w0.x = acc[mt][nt][0] + bs(o0, 0);
        w0.y = acc[mt][nt][1] + bs(o0, 1);
        w1.x = acc[mt][nt][2] + bs(o1, 0);
        w1.y = acc[mt][nt][3] + bs(o1, 1);
        *(float2*)(out + b0) = w0;
        *(float2*)(out + b1) = w1;
      }
    }
  }
#undef HSA
#undef HSB
#undef RDA
#undef RDB
#undef MM
#undef BAR
#undef WAITV
}

extern "C" void kernel_launch(void* const* d_in, const int* in_sizes, int n_in,
                              void* d_out, int out_size, void* d_ws, size_t ws_size,
                              hipStream_t stream) {
  const float* x    = (const float*)d_in[0];
  const float* w    = (const float*)d_in[1];
  const float* bias = (const float*)d_in[2];
  float* out = (float*)d_out;
  char* ws = (char*)d_ws;
  __bf16* xpad = (__bf16*)ws;
  __bf16* amat = (__bf16*)(ws + A_OFF);

  prep_x<<<dim3(66, 8), 256, 0, stream>>>(x, xpad);
  prep_w3<<<dim3(128), 256, 0, stream>>>(w, amat);
  deconv_mfma<<<dim3(2 * NT_N), 512, 0, stream>>>(xpad, amat, bias, out);
}